// Round 1
// baseline (1934.687 us; speedup 1.0000x reference)
//
#include <hip/hip_runtime.h>
#include <math.h>

#define BATCH 1024
#define HID 256
#define GH 9
#define GW 9

struct ProjDesc {
    const float* left;   // [B][H] or nullptr (zeros)
    const float* up;     // [B][H] or nullptr (zeros)
    const float* prev;   // [B][H]
    const float* W;      // [H][3H] row-major
    const float* bias;   // [H]
    float* out;          // [B][H]
};
struct ProjBatchArgs { ProjDesc d[18]; };

struct CellDesc {
    const float* ph;     // [B][H]
    const float* pc;     // [B][H]
    const float* Whh;    // [4H][H] row-major
    const float* Wih;    // [4H]
    const float* bih;    // [4H]
    const float* bhh;    // [4H]
    const float* xcol;   // x + i*GW + j, stride 81 per batch
    float* gh;           // [B][H]
    float* gc;           // [B][H]
};
struct CellBatchArgs { CellDesc d[9]; };

// C[64x64] tile of  out[b][n] = sum_k comb[b][k] * W[n][k] + bias[n]
// comb = concat(left, up, prev) along k (each segment H=256 wide).
__global__ __launch_bounds__(256) void proj_kernel(ProjBatchArgs args) {
    const ProjDesc pd = args.d[blockIdx.z];
    __shared__ float At[32][68];   // [k][batch]
    __shared__ float Wt[32][68];   // [k][unit]
    const int tid = threadIdx.x;
    const int tx = tid & 15, ty = tid >> 4;
    const int lr = tid >> 2;          // 0..63
    const int lc = (tid & 3) * 8;     // 0,8,16,24
    const int b0 = blockIdx.x * 64;
    const int n0 = blockIdx.y * 64;
    float acc[4][4] = {};
    const float* Wrow = pd.W + (size_t)(n0 + lr) * (3 * HID);

    for (int kt = 0; kt < 24; ++kt) {
        const int k0 = kt * 32;
        const int seg = k0 >> 8;
        const float* src = (seg == 0) ? pd.left : (seg == 1 ? pd.up : pd.prev);
        float av[8], wv[8];
        if (src) {
            const float* p = src + (size_t)(b0 + lr) * HID + (k0 & 255) + lc;
            float4 v0 = *(const float4*)p;
            float4 v1 = *(const float4*)(p + 4);
            av[0]=v0.x; av[1]=v0.y; av[2]=v0.z; av[3]=v0.w;
            av[4]=v1.x; av[5]=v1.y; av[6]=v1.z; av[7]=v1.w;
        } else {
            #pragma unroll
            for (int m = 0; m < 8; ++m) av[m] = 0.f;
        }
        {
            const float* p = Wrow + k0 + lc;
            float4 v0 = *(const float4*)p;
            float4 v1 = *(const float4*)(p + 4);
            wv[0]=v0.x; wv[1]=v0.y; wv[2]=v0.z; wv[3]=v0.w;
            wv[4]=v1.x; wv[5]=v1.y; wv[6]=v1.z; wv[7]=v1.w;
        }
        __syncthreads();
        #pragma unroll
        for (int m = 0; m < 8; ++m) At[lc + m][lr] = av[m];
        #pragma unroll
        for (int m = 0; m < 8; ++m) Wt[lc + m][lr] = wv[m];
        __syncthreads();
        #pragma unroll
        for (int kk = 0; kk < 32; ++kk) {
            const float4 a = *(const float4*)&At[kk][ty * 4];
            const float4 w = *(const float4*)&Wt[kk][tx * 4];
            const float ar[4] = {a.x, a.y, a.z, a.w};
            const float wr[4] = {w.x, w.y, w.z, w.w};
            #pragma unroll
            for (int r = 0; r < 4; ++r)
                #pragma unroll
                for (int c = 0; c < 4; ++c)
                    acc[r][c] += ar[r] * wr[c];
        }
    }
    const float4 bv = *(const float4*)(pd.bias + n0 + tx * 4);
    const float bb[4] = {bv.x, bv.y, bv.z, bv.w};
    #pragma unroll
    for (int r = 0; r < 4; ++r) {
        const int b = b0 + ty * 4 + r;
        float4 v;
        v.x = acc[r][0] + bb[0];
        v.y = acc[r][1] + bb[1];
        v.z = acc[r][2] + bb[2];
        v.w = acc[r][3] + bb[3];
        *(float4*)(pd.out + (size_t)b * HID + n0 + tx * 4) = v;
    }
}

// gates[b][g*H+u] = x[b]*Wih[g*H+u] + bih + bhh + sum_k ph[b][k]*Whh[g*H+u][k]
// tile: 64 batch x 16 units x 4 gates; col c = t*4+g so thread tx holds all 4
// gates of unit u0+tx for its 4 batch rows -> LSTM elementwise fully local.
__global__ __launch_bounds__(256) void cell_kernel(CellBatchArgs args) {
    const CellDesc cd = args.d[blockIdx.z];
    __shared__ float Pt[32][68];
    __shared__ float Wt[32][68];
    const int tid = threadIdx.x;
    const int tx = tid & 15, ty = tid >> 4;
    const int lr = tid >> 2;
    const int lc = (tid & 3) * 8;
    const int b0 = blockIdx.x * 64;
    const int u0 = blockIdx.y * 16;
    float acc[4][4] = {};
    const int t_r = lr >> 2, g_r = lr & 3;
    const float* Wrow = cd.Whh + (size_t)(g_r * HID + u0 + t_r) * HID;

    for (int kt = 0; kt < 8; ++kt) {
        const int k0 = kt * 32;
        float pv[8], wv[8];
        {
            const float* p = cd.ph + (size_t)(b0 + lr) * HID + k0 + lc;
            float4 v0 = *(const float4*)p;
            float4 v1 = *(const float4*)(p + 4);
            pv[0]=v0.x; pv[1]=v0.y; pv[2]=v0.z; pv[3]=v0.w;
            pv[4]=v1.x; pv[5]=v1.y; pv[6]=v1.z; pv[7]=v1.w;
        }
        {
            const float* p = Wrow + k0 + lc;
            float4 v0 = *(const float4*)p;
            float4 v1 = *(const float4*)(p + 4);
            wv[0]=v0.x; wv[1]=v0.y; wv[2]=v0.z; wv[3]=v0.w;
            wv[4]=v1.x; wv[5]=v1.y; wv[6]=v1.z; wv[7]=v1.w;
        }
        __syncthreads();
        #pragma unroll
        for (int m = 0; m < 8; ++m) Pt[lc + m][lr] = pv[m];
        #pragma unroll
        for (int m = 0; m < 8; ++m) Wt[lc + m][lr] = wv[m];
        __syncthreads();
        #pragma unroll
        for (int kk = 0; kk < 32; ++kk) {
            const float4 a = *(const float4*)&Pt[kk][ty * 4];
            const float4 w = *(const float4*)&Wt[kk][tx * 4];
            const float ar[4] = {a.x, a.y, a.z, a.w};
            const float wr[4] = {w.x, w.y, w.z, w.w};
            #pragma unroll
            for (int r = 0; r < 4; ++r)
                #pragma unroll
                for (int c = 0; c < 4; ++c)
                    acc[r][c] += ar[r] * wr[c];
        }
    }
    const int u = u0 + tx;
    float wih[4], bias[4];
    #pragma unroll
    for (int g = 0; g < 4; ++g) {
        const int rr = g * HID + u;
        wih[g] = cd.Wih[rr];
        bias[g] = cd.bih[rr] + cd.bhh[rr];
    }
    #pragma unroll
    for (int r = 0; r < 4; ++r) {
        const int b = b0 + ty * 4 + r;
        const float xv = cd.xcol[(size_t)b * (GH * GW)];
        const float gi = acc[r][0] + xv * wih[0] + bias[0];
        const float gf = acc[r][1] + xv * wih[1] + bias[1];
        const float gg = acc[r][2] + xv * wih[2] + bias[2];
        const float go = acc[r][3] + xv * wih[3] + bias[3];
        const float i_ = 1.f / (1.f + expf(-gi));
        const float f_ = 1.f / (1.f + expf(-gf));
        const float o_ = 1.f / (1.f + expf(-go));
        const float g_ = tanhf(gg);
        const float c0 = cd.pc[(size_t)b * HID + u];
        const float cn = f_ * c0 + i_ * g_;
        const float hn = o_ * tanhf(cn);
        cd.gh[(size_t)b * HID + u] = hn;
        cd.gc[(size_t)b * HID + u] = cn;
    }
}

__global__ __launch_bounds__(256) void final_kernel(
        const float* __restrict__ gh88, const float* __restrict__ gc88,
        const float* __restrict__ Wout, const float* __restrict__ bout,
        float* __restrict__ out, float* __restrict__ fh, float* __restrict__ fc) {
    const int tid = blockIdx.x * blockDim.x + threadIdx.x;
    const int nth = gridDim.x * blockDim.x;
    for (int idx = tid; idx < BATCH * HID; idx += nth) {
        fh[idx] = gh88[idx];
        fc[idx] = gc88[idx];
    }
    if (tid < BATCH) {
        float s = bout[0];
        for (int k = 0; k < HID; ++k) s += gh88[(size_t)tid * HID + k] * Wout[k];
        s = fmaxf(s, 0.f);
        out[tid] = 1.f / (1.f + expf(-s));
    }
}

extern "C" void kernel_launch(void* const* d_in, const int* in_sizes, int n_in,
                              void* d_out, int out_size, void* d_ws, size_t ws_size,
                              hipStream_t stream) {
    const float* x      = (const float*)d_in[0];
    const float* h_ext  = (const float*)d_in[1];
    const float* c_ext  = (const float*)d_in[2];
    const float* grid_h = (const float*)d_in[3];
    const float* grid_c = (const float*)d_in[4];
    const float* W_hp   = (const float*)d_in[5];
    const float* b_hp   = (const float*)d_in[6];
    const float* W_cp   = (const float*)d_in[7];
    const float* b_cp   = (const float*)d_in[8];
    const float* W_ih   = (const float*)d_in[9];
    const float* W_hh   = (const float*)d_in[10];
    const float* b_ih   = (const float*)d_in[11];
    const float* b_hh   = (const float*)d_in[12];
    const float* W_out  = (const float*)d_in[13];
    const float* b_out  = (const float*)d_in[14];

    float* out = (float*)d_out;
    float* fh  = out + BATCH * 1;
    float* fc  = fh + BATCH * HID;
    float* gh  = fc + BATCH * HID;
    float* gc  = gh + (size_t)GH * GW * BATCH * HID;

    float* ws = (float*)d_ws;   // need 18*B*H floats = 18 MB

    for (int d = 0; d <= GH + GW - 2; ++d) {
        const int i_lo = d > (GW - 1) ? d - (GW - 1) : 0;
        const int i_hi = d < (GH - 1) ? d : (GH - 1);
        const int nc = i_hi - i_lo + 1;
        ProjBatchArgs pa{};
        CellBatchArgs ca{};
        for (int s = 0; s < nc; ++s) {
            const int i = i_lo + s, j = d - i;
            const int k = i * GW + j;
            const float *hl, *cl, *hu, *cu;
            if (i == 0 && j == 0)      { hl = h_ext; cl = c_ext; }
            else if (j > 0)            { hl = gh + (size_t)(i * GW + j - 1) * BATCH * HID;
                                         cl = gc + (size_t)(i * GW + j - 1) * BATCH * HID; }
            else                       { hl = nullptr; cl = nullptr; }
            if (i > 0)                 { hu = gh + (size_t)((i - 1) * GW + j) * BATCH * HID;
                                         cu = gc + (size_t)((i - 1) * GW + j) * BATCH * HID; }
            else                       { hu = nullptr; cu = nullptr; }
            const float* hp = grid_h + (size_t)k * BATCH * HID;
            const float* cp = grid_c + (size_t)k * BATCH * HID;
            float* ph = ws + (size_t)s * 2 * BATCH * HID;
            float* pc = ph + BATCH * HID;
            pa.d[2 * s + 0] = { hl, hu, hp, W_hp + (size_t)k * HID * 3 * HID,
                                b_hp + (size_t)k * HID, ph };
            pa.d[2 * s + 1] = { cl, cu, cp, W_cp + (size_t)k * HID * 3 * HID,
                                b_cp + (size_t)k * HID, pc };
            ca.d[s] = { ph, pc,
                        W_hh + (size_t)k * 4 * HID * HID,
                        W_ih + (size_t)k * 4 * HID,
                        b_ih + (size_t)k * 4 * HID,
                        b_hh + (size_t)k * 4 * HID,
                        x + i * GW + j,
                        gh + (size_t)k * BATCH * HID,
                        gc + (size_t)k * BATCH * HID };
        }
        proj_kernel<<<dim3(16, 4, 2 * nc), 256, 0, stream>>>(pa);
        cell_kernel<<<dim3(16, 16, nc), 256, 0, stream>>>(ca);
    }
    final_kernel<<<dim3(64), 256, 0, stream>>>(
        gh + (size_t)80 * BATCH * HID, gc + (size_t)80 * BATCH * HID,
        W_out, b_out, out, fh, fc);
}

// Round 2
// 1081.200 us; speedup vs baseline: 1.7894x; 1.7894x over previous
//
#include <hip/hip_runtime.h>
#include <math.h>

#define BATCH 1024
#define HID 256

typedef __bf16 bf16_t;
typedef __bf16 bf16x8 __attribute__((ext_vector_type(8)));
typedef float f32x4 __attribute__((ext_vector_type(4)));

struct ProjDesc {
    const float* left;   // [B][H] or nullptr (zeros)
    const float* up;     // [B][H] or nullptr (zeros)
    const float* prev;   // [B][H]
    const float* W;      // [H][3H] row-major
    const float* bias;   // [H]
    float* out;          // [B][H]
};
struct ProjBatchArgs { ProjDesc d[18]; };

struct CellDesc {
    const float* ph;     // [B][H]
    const float* pc;     // [B][H]
    const float* Whh;    // [4H][H] row-major
    const float* Wih;    // [4H]
    const float* bih;    // [4H]
    const float* bhh;    // [4H]
    const float* xcol;   // x + i*GW + j, stride 81 per batch
    float* gh;           // [B][H]
    float* gc;           // [B][H]
};
struct CellBatchArgs { CellDesc d[9]; };

__device__ inline bf16x8 cvt8(const float4 a, const float4 b) {
    bf16x8 r;
    r[0] = (bf16_t)a.x; r[1] = (bf16_t)a.y; r[2] = (bf16_t)a.z; r[3] = (bf16_t)a.w;
    r[4] = (bf16_t)b.x; r[5] = (bf16_t)b.y; r[6] = (bf16_t)b.z; r[7] = (bf16_t)b.w;
    return r;
}

// out[b][n] = sum_k comb[b][k] * W[n][k] + bias[n], comb = [left|up|prev].
// Tile: 64 batch x 128 units, BK=32, bf16 MFMA 16x16x32, fp32 accum.
// Waves 2x2: wave tile 32m x 64n -> 2x4 fragments.
__global__ __launch_bounds__(256) void proj_kernel(ProjBatchArgs args) {
    const ProjDesc pd = args.d[blockIdx.z];
    __shared__ bf16_t Asm[64][40];
    __shared__ bf16_t Bsm[128][40];
    const int t = threadIdx.x;
    const int lane = t & 63, wid = t >> 6;
    const int wm = wid & 1, wn = wid >> 1;
    const int ln = lane & 15, lh = lane >> 4;
    const int b0 = blockIdx.x * 64;
    const int n0 = blockIdx.y * 128;
    const int lr_a = t >> 2, lq_a = (t & 3) * 8;   // A: 64 rows x 32k, 8 f/thread
    const int lr_b = t >> 1, lq_b = (t & 1) * 16;  // B: 128 rows x 32k, 16 f/thread

    f32x4 acc[2][4] = {};
    const float* wrow = pd.W + (size_t)(n0 + lr_b) * (3 * HID) + lq_b;
    const float* srcs[3] = { pd.left, pd.up, pd.prev };

    for (int seg = 0; seg < 3; ++seg) {
        const float* sp = srcs[seg];
        if (!sp) continue;  // zero segment contributes nothing (uniform skip)
        const float* arow = sp + (size_t)(b0 + lr_a) * HID + lq_a;
        const float* wseg = wrow + seg * HID;
        for (int kb = 0; kb < 8; ++kb) {
            const float4 a0 = *(const float4*)(arow + kb * 32);
            const float4 a1 = *(const float4*)(arow + kb * 32 + 4);
            const float4 w0 = *(const float4*)(wseg + kb * 32);
            const float4 w1 = *(const float4*)(wseg + kb * 32 + 4);
            const float4 w2 = *(const float4*)(wseg + kb * 32 + 8);
            const float4 w3 = *(const float4*)(wseg + kb * 32 + 12);
            const bf16x8 av  = cvt8(a0, a1);
            const bf16x8 bv0 = cvt8(w0, w1);
            const bf16x8 bv1 = cvt8(w2, w3);
            __syncthreads();
            *(bf16x8*)&Asm[lr_a][lq_a] = av;
            *(bf16x8*)&Bsm[lr_b][lq_b] = bv0;
            *(bf16x8*)&Bsm[lr_b][lq_b + 8] = bv1;
            __syncthreads();
            bf16x8 af[2], bfr[4];
            #pragma unroll
            for (int mf = 0; mf < 2; ++mf)
                af[mf] = *(const bf16x8*)&Asm[wm * 32 + mf * 16 + ln][lh * 8];
            #pragma unroll
            for (int nf = 0; nf < 4; ++nf)
                bfr[nf] = *(const bf16x8*)&Bsm[wn * 64 + nf * 16 + ln][lh * 8];
            #pragma unroll
            for (int mf = 0; mf < 2; ++mf)
                #pragma unroll
                for (int nf = 0; nf < 4; ++nf)
                    acc[mf][nf] = __builtin_amdgcn_mfma_f32_16x16x32_bf16(
                        af[mf], bfr[nf], acc[mf][nf], 0, 0, 0);
        }
    }
    #pragma unroll
    for (int nf = 0; nf < 4; ++nf) {
        const int n = n0 + wn * 64 + nf * 16 + ln;
        const float bias = pd.bias[n];
        #pragma unroll
        for (int mf = 0; mf < 2; ++mf)
            #pragma unroll
            for (int r = 0; r < 4; ++r) {
                const int b = b0 + wm * 32 + mf * 16 + lh * 4 + r;
                pd.out[(size_t)b * HID + n] = acc[mf][nf][r] + bias;
            }
    }
}

// gates[b][g*H+u] then fused LSTM elementwise.
// Tile: 128 batch x (4 gates x 32 units). B-tile row c = g*32 + du.
// Waves 2x2: wave = 64m x (4 gates x 16 du); fragment nf == gate -> each
// thread holds all 4 gates of its unit: elementwise fully local.
__global__ __launch_bounds__(256) void cell_kernel(CellBatchArgs args) {
    const CellDesc cd = args.d[blockIdx.z];
    __shared__ bf16_t Psm[128][40];
    __shared__ bf16_t Wsm[128][40];
    const int t = threadIdx.x;
    const int lane = t & 63, wid = t >> 6;
    const int wm = wid & 1, wn = wid >> 1;
    const int ln = lane & 15, lh = lane >> 4;
    const int b0 = blockIdx.x * 128;
    const int u0 = blockIdx.y * 32;
    const int lr = t >> 1, lq = (t & 1) * 16;

    f32x4 acc[4][4] = {};
    const float* prow = cd.ph + (size_t)(b0 + lr) * HID + lq;
    const int cg = lr >> 5, cdu = lr & 31;
    const float* wrow = cd.Whh + (size_t)(cg * HID + u0 + cdu) * HID + lq;

    for (int kb = 0; kb < 8; ++kb) {
        const float4 p0 = *(const float4*)(prow + kb * 32);
        const float4 p1 = *(const float4*)(prow + kb * 32 + 4);
        const float4 p2 = *(const float4*)(prow + kb * 32 + 8);
        const float4 p3 = *(const float4*)(prow + kb * 32 + 12);
        const float4 w0 = *(const float4*)(wrow + kb * 32);
        const float4 w1 = *(const float4*)(wrow + kb * 32 + 4);
        const float4 w2 = *(const float4*)(wrow + kb * 32 + 8);
        const float4 w3 = *(const float4*)(wrow + kb * 32 + 12);
        const bf16x8 pv0 = cvt8(p0, p1), pv1 = cvt8(p2, p3);
        const bf16x8 wv0 = cvt8(w0, w1), wv1 = cvt8(w2, w3);
        __syncthreads();
        *(bf16x8*)&Psm[lr][lq] = pv0;
        *(bf16x8*)&Psm[lr][lq + 8] = pv1;
        *(bf16x8*)&Wsm[lr][lq] = wv0;
        *(bf16x8*)&Wsm[lr][lq + 8] = wv1;
        __syncthreads();
        bf16x8 af[4], bfr[4];
        #pragma unroll
        for (int mf = 0; mf < 4; ++mf)
            af[mf] = *(const bf16x8*)&Psm[wm * 64 + mf * 16 + ln][lh * 8];
        #pragma unroll
        for (int g = 0; g < 4; ++g)
            bfr[g] = *(const bf16x8*)&Wsm[g * 32 + wn * 16 + ln][lh * 8];
        #pragma unroll
        for (int mf = 0; mf < 4; ++mf)
            #pragma unroll
            for (int g = 0; g < 4; ++g)
                acc[mf][g] = __builtin_amdgcn_mfma_f32_16x16x32_bf16(
                    af[mf], bfr[g], acc[mf][g], 0, 0, 0);
    }

    const int u = u0 + wn * 16 + ln;
    float wih[4], bsum[4];
    #pragma unroll
    for (int g = 0; g < 4; ++g) {
        const int n = g * HID + u;
        wih[g] = cd.Wih[n];
        bsum[g] = cd.bih[n] + cd.bhh[n];
    }
    #pragma unroll
    for (int mf = 0; mf < 4; ++mf)
        #pragma unroll
        for (int r = 0; r < 4; ++r) {
            const int b = b0 + wm * 64 + mf * 16 + lh * 4 + r;
            const float xv = cd.xcol[(size_t)b * 81];
            const float gi = acc[mf][0][r] + xv * wih[0] + bsum[0];
            const float gf = acc[mf][1][r] + xv * wih[1] + bsum[1];
            const float gg = acc[mf][2][r] + xv * wih[2] + bsum[2];
            const float go = acc[mf][3][r] + xv * wih[3] + bsum[3];
            const float i_ = 1.f / (1.f + expf(-gi));
            const float f_ = 1.f / (1.f + expf(-gf));
            const float o_ = 1.f / (1.f + expf(-go));
            const float g_ = tanhf(gg);
            const float c0 = cd.pc[(size_t)b * HID + u];
            const float cn = f_ * c0 + i_ * g_;
            const float hn = o_ * tanhf(cn);
            cd.gh[(size_t)b * HID + u] = hn;
            cd.gc[(size_t)b * HID + u] = cn;
        }
}

__global__ __launch_bounds__(256) void final_kernel(
        const float* __restrict__ gh88, const float* __restrict__ gc88,
        const float* __restrict__ Wout, const float* __restrict__ bout,
        float* __restrict__ out, float* __restrict__ fh, float* __restrict__ fc) {
    const int tid = blockIdx.x * blockDim.x + threadIdx.x;
    const int nth = gridDim.x * blockDim.x;
    for (int idx = tid; idx < BATCH * HID; idx += nth) {
        fh[idx] = gh88[idx];
        fc[idx] = gc88[idx];
    }
    if (tid < BATCH) {
        float s = bout[0];
        for (int k = 0; k < HID; ++k) s += gh88[(size_t)tid * HID + k] * Wout[k];
        s = fmaxf(s, 0.f);
        out[tid] = 1.f / (1.f + expf(-s));
    }
}

extern "C" void kernel_launch(void* const* d_in, const int* in_sizes, int n_in,
                              void* d_out, int out_size, void* d_ws, size_t ws_size,
                              hipStream_t stream) {
    const float* x      = (const float*)d_in[0];
    const float* h_ext  = (const float*)d_in[1];
    const float* c_ext  = (const float*)d_in[2];
    const float* grid_h = (const float*)d_in[3];
    const float* grid_c = (const float*)d_in[4];
    const float* W_hp   = (const float*)d_in[5];
    const float* b_hp   = (const float*)d_in[6];
    const float* W_cp   = (const float*)d_in[7];
    const float* b_cp   = (const float*)d_in[8];
    const float* W_ih   = (const float*)d_in[9];
    const float* W_hh   = (const float*)d_in[10];
    const float* b_ih   = (const float*)d_in[11];
    const float* b_hh   = (const float*)d_in[12];
    const float* W_out  = (const float*)d_in[13];
    const float* b_out  = (const float*)d_in[14];

    float* out = (float*)d_out;
    float* fh  = out + BATCH * 1;
    float* fc  = fh + BATCH * HID;
    float* gh  = fc + BATCH * HID;
    float* gc  = gh + (size_t)81 * BATCH * HID;

    float* ws = (float*)d_ws;   // 18 * B * H floats = 18 MB

    for (int d = 0; d <= 16; ++d) {
        const int i_lo = d > 8 ? d - 8 : 0;
        const int i_hi = d < 8 ? d : 8;
        const int nc = i_hi - i_lo + 1;
        ProjBatchArgs pa{};
        CellBatchArgs ca{};
        for (int s = 0; s < nc; ++s) {
            const int i = i_lo + s, j = d - i;
            const int k = i * 9 + j;
            const float *hl, *cl, *hu, *cu;
            if (i == 0 && j == 0)      { hl = h_ext; cl = c_ext; }
            else if (j > 0)            { hl = gh + (size_t)(k - 1) * BATCH * HID;
                                         cl = gc + (size_t)(k - 1) * BATCH * HID; }
            else                       { hl = nullptr; cl = nullptr; }
            if (i > 0)                 { hu = gh + (size_t)(k - 9) * BATCH * HID;
                                         cu = gc + (size_t)(k - 9) * BATCH * HID; }
            else                       { hu = nullptr; cu = nullptr; }
            const float* hp = grid_h + (size_t)k * BATCH * HID;
            const float* cp = grid_c + (size_t)k * BATCH * HID;
            float* ph = ws + (size_t)s * 2 * BATCH * HID;
            float* pc = ph + BATCH * HID;
            pa.d[2 * s + 0] = { hl, hu, hp, W_hp + (size_t)k * HID * 3 * HID,
                                b_hp + (size_t)k * HID, ph };
            pa.d[2 * s + 1] = { cl, cu, cp, W_cp + (size_t)k * HID * 3 * HID,
                                b_cp + (size_t)k * HID, pc };
            ca.d[s] = { ph, pc,
                        W_hh + (size_t)k * 4 * HID * HID,
                        W_ih + (size_t)k * 4 * HID,
                        b_ih + (size_t)k * 4 * HID,
                        b_hh + (size_t)k * 4 * HID,
                        x + i * 9 + j,
                        gh + (size_t)k * BATCH * HID,
                        gc + (size_t)k * BATCH * HID };
        }
        proj_kernel<<<dim3(16, 2, 2 * nc), 256, 0, stream>>>(pa);
        cell_kernel<<<dim3(8, 8, nc), 256, 0, stream>>>(ca);
    }
    final_kernel<<<dim3(64), 256, 0, stream>>>(
        gh + (size_t)80 * BATCH * HID, gc + (size_t)80 * BATCH * HID,
        W_out, b_out, out, fh, fc);
}